// Round 2
// baseline (722.200 us; speedup 1.0000x reference)
//
#include <hip/hip_runtime.h>
#include <hip/hip_fp16.h>
#include <math.h>

#define PI_F 3.14159265358979323846f

__device__ __forceinline__ unsigned br8(unsigned v){ return __brev(v) >> 24; }

__device__ __forceinline__ float packh2(float re, float im){
  __half2 h = __floats2half2_rn(re, im);
  return __builtin_bit_cast(float, h);
}
__device__ __forceinline__ float2 unpackh2(float p){
  return __half22float2(__builtin_bit_cast(__half2, p));
}

// Fill master twiddle table tw[k] = (cos(pi k/128), sin(pi k/128)), k in [0,128).
__device__ __forceinline__ void fill_tw(float2* tw, int tid){
  if (tid < 128){
    float s, c;
    sincosf(PI_F * (float)tid * (1.0f/128.0f), &s, &c);
    tw[tid] = make_float2(c, s);
  }
  __syncthreads();
}

// 256-pt radix-2 DIT on one (or two) contiguous 256-float2 LDS rows.
// Input bit-reversed, output natural. INV=false: e^{-i...}; INV=true: e^{+i...} (unnormalized).
template<bool INV>
__device__ __forceinline__ void dit_row2(float2* A, float2* B, const float2* tw, int lane){
  #pragma unroll
  for (int lh = 0; lh < 8; ++lh){
    const int half = 1 << lh;
    #pragma unroll
    for (int k = 0; k < 2; ++k){
      const int idx = lane + (k << 6);
      const int pos = idx & (half - 1);
      const int base = ((idx >> lh) << (lh + 1)) + pos;
      const float2 w = tw[pos << (7 - lh)];
      const float wr = w.x;
      const float wi = INV ? w.y : -w.y;
      {
        const float2 a = A[base], b = A[base + half];
        const float tr = wr * b.x - wi * b.y;
        const float ti = wr * b.y + wi * b.x;
        A[base]        = make_float2(a.x + tr, a.y + ti);
        A[base + half] = make_float2(a.x - tr, a.y - ti);
      }
      if (B){
        const float2 a = B[base], b = B[base + half];
        const float tr = wr * b.x - wi * b.y;
        const float ti = wr * b.y + wi * b.x;
        B[base]        = make_float2(a.x + tr, a.y + ti);
        B[base + half] = make_float2(a.x - tr, a.y - ti);
      }
    }
    __syncthreads();
  }
}

// 256-pt radix-2 DIT over 8 interleaved columns at float2-pitch 9.
template<bool INV>
__device__ __forceinline__ void dit_cols(float2* buf, const float2* tw, int c, int sub){
  #pragma unroll
  for (int lh = 0; lh < 8; ++lh){
    const int half = 1 << lh;
    #pragma unroll
    for (int k = 0; k < 4; ++k){
      const int idx = sub + (k << 5);
      const int pos = idx & (half - 1);
      const int base = ((idx >> lh) << (lh + 1)) + pos;
      const float2 w = tw[pos << (7 - lh)];
      const float wr = w.x;
      const float wi = INV ? w.y : -w.y;
      float2* pa = buf + (base) * 9 + c;
      float2* pb = buf + (base + half) * 9 + c;
      const float2 a = *pa, b = *pb;
      const float tr = wr * b.x - wi * b.y;
      const float ti = wr * b.y + wi * b.x;
      *pa = make_float2(a.x + tr, a.y + ti);
      *pb = make_float2(a.x - tr, a.y - ti);
    }
    __syncthreads();
  }
}

// K1: forward row FFT (over j). 4 rows/block. xs/SPEC pre-offset per slice.
__global__ __launch_bounds__(256) void k1_row(const float* __restrict__ xs, float2* __restrict__ SPEC){
  __shared__ float2 tw[128];
  __shared__ __align__(16) float2 buf[4][256];
  const int tid = threadIdx.x;
  fill_tw(tw, tid);
  const int grp = tid >> 6, lane = tid & 63;
  const int rs = blockIdx.x * 4 + grp;
  const int j0 = lane << 2;
  const float4 xv = *(const float4*)(xs + (size_t)rs * 256 + j0);
  float2* rb = buf[grp];
  rb[br8(j0 + 0)] = make_float2(xv.x, 0.f);
  rb[br8(j0 + 1)] = make_float2(xv.y, 0.f);
  rb[br8(j0 + 2)] = make_float2(xv.z, 0.f);
  rb[br8(j0 + 3)] = make_float2(xv.w, 0.f);
  __syncthreads();
  dit_row2<false>(rb, (float2*)nullptr, tw, lane);
  float4* dst = (float4*)(SPEC + (size_t)rs * 256);
  const float4* src = (const float4*)rb;
  dst[lane * 2]     = src[lane * 2];
  dst[lane * 2 + 1] = src[lane * 2 + 1];
}

// K2: per (image, 8-col tile): col FFT -> F[v][u]; both Riesz filters; 2 col IFFTs;
// write U1,U2 packed fp16 IN PLACE over this block's own S bytes.
__global__ __launch_bounds__(256) void k2_col(float2* SPEC, const float* __restrict__ km){
  __shared__ float2 tw[128];
  __shared__ float2 bufA[256 * 9];
  __shared__ float2 bufB[256 * 9];
  const int tid = threadIdx.x;
  fill_tw(tw, tid);
  const int b_local = blockIdx.x >> 5;
  const int u0 = (blockIdx.x & 31) << 3;
  const int c = tid & 7, sub = tid >> 3;
  const size_t rowbase = (size_t)b_local * 256;

  #pragma unroll
  for (int k = 0; k < 8; ++k){
    const int l = tid + (k << 8);
    const int r = l >> 3, cc = l & 7;
    bufA[br8(r) * 9 + cc] = SPEC[(rowbase + r) * 256 + u0 + cc];
  }
  __syncthreads();
  dit_cols<false>(bufA, tw, c, sub);        // F[v][u] natural in bufA

  float s8[8];
  #pragma unroll
  for (int k = 0; k < 8; ++k){
    const int l = tid + (k << 8);
    const int v = l >> 3, cc = l & 7;
    const int u = u0 + cc;
    const float kmv = km[u * 256 + v];
    float sp = fmaxf(kmv, 0.f) + log1pf(expf(-fabsf(kmv)));
    sp = fminf(fmaxf(sp, 1e-3f), 10.f);
    const float fu = (float)(u + 1), fv = (float)(v + 1);
    const float s = sp / (sqrtf(fu * fu + fv * fv) + 1e-6f) * (1.0f / 65536.0f);
    s8[k] = s;
    const float2 F = bufA[v * 9 + cc];
    const float s1 = fv * s;                // dx filter: -i*(v+1)*s * F
    bufB[br8(v) * 9 + cc] = make_float2(s1 * F.y, -s1 * F.x);
  }
  __syncthreads();
  dit_cols<true>(bufB, tw, c, sub);

  float u1h[8];
  #pragma unroll
  for (int k = 0; k < 8; ++k){
    const int l = tid + (k << 8);
    const int i = l >> 3, cc = l & 7;
    const float2 f1 = bufB[i * 9 + cc];
    u1h[k] = packh2(f1.x, f1.y);
  }
  __syncthreads();                          // stash reads done before refill

  #pragma unroll
  for (int k = 0; k < 8; ++k){
    const int l = tid + (k << 8);
    const int v = l >> 3, cc = l & 7;
    const int u = u0 + cc;
    const float fu = (float)(u + 1);
    const float2 F = bufA[v * 9 + cc];
    const float s2 = fu * s8[k];            // dy filter: -i*(u+1)*s * F
    bufB[br8(v) * 9 + cc] = make_float2(s2 * F.y, -s2 * F.x);
  }
  __syncthreads();
  dit_cols<true>(bufB, tw, c, sub);

  #pragma unroll
  for (int k = 0; k < 8; ++k){
    const int l = tid + (k << 8);
    const int i = l >> 3, cc = l & 7;
    const float2 f2 = bufB[i * 9 + cc];
    float2 slot;
    slot.x = u1h[k];
    slot.y = packh2(f2.x, f2.y);
    SPEC[(rowbase + i) * 256 + u0 + cc] = slot;   // own bytes only
  }
}

// K3: row IFFT of packed U1/U2, pointwise A/P/theta/A_boost.
// A (f32) -> Ap (d_out region), P/T (fp16) -> PTp rows of 1024 B.
__global__ __launch_bounds__(256) void k3_rowinv(const float* __restrict__ xs,
    const float2* __restrict__ SPEC, float* __restrict__ Ap, char* __restrict__ PTp,
    const float* __restrict__ ampw, const float* __restrict__ ampb){
  __shared__ float2 tw[128];
  __shared__ __align__(16) float2 b1[4][256];
  __shared__ __align__(16) float2 b2[4][256];
  const int tid = threadIdx.x;
  fill_tw(tw, tid);
  const int grp = tid >> 6, lane = tid & 63;
  const int rs = blockIdx.x * 4 + grp;
  const int j0 = lane << 2;
  const float4* srow = (const float4*)(SPEC + (size_t)rs * 256);
  const float4 qa = srow[lane * 2], qb = srow[lane * 2 + 1];
  b1[grp][br8(j0 + 0)] = unpackh2(qa.x); b2[grp][br8(j0 + 0)] = unpackh2(qa.y);
  b1[grp][br8(j0 + 1)] = unpackh2(qa.z); b2[grp][br8(j0 + 1)] = unpackh2(qa.w);
  b1[grp][br8(j0 + 2)] = unpackh2(qb.x); b2[grp][br8(j0 + 2)] = unpackh2(qb.y);
  b1[grp][br8(j0 + 3)] = unpackh2(qb.z); b2[grp][br8(j0 + 3)] = unpackh2(qb.w);
  __syncthreads();
  dit_row2<true>(b1[grp], b2[grp], tw, lane);

  const float aw = *ampw, ab = *ampb;
  const float4 xv = *(const float4*)(xs + (size_t)rs * 256 + j0);
  const float xa[4] = {xv.x, xv.y, xv.z, xv.w};
  float A4[4], P4[4], T4[4];
  #pragma unroll
  for (int k = 0; k < 4; ++k){
    const float2 r1 = b1[grp][j0 + k];
    const float2 r2 = b2[grp][j0 + k];
    const float R1 = sqrtf(r1.x * r1.x + r1.y * r1.y) + 1e-6f;
    const float R2 = sqrtf(r2.x * r2.x + r2.y * r2.y) + 1e-6f;
    const float xvv = xa[k];
    const float A = sqrtf(fmaxf(xvv * xvv + R1 * R1 + R2 * R2, 0.f) + 1e-6f);
    P4[k] = atan2f(sqrtf(R1 * R1 + R2 * R2) + 1e-6f, xvv + 1e-6f);
    T4[k] = atan2f(R2, R1 + 1e-6f);
    A4[k] = A + fmaxf(aw * A + ab, 0.f);
  }
  *(float4*)(Ap + (size_t)rs * 256 + j0) = make_float4(A4[0], A4[1], A4[2], A4[3]);
  float2 pk, tk2;
  pk.x  = packh2(P4[0], P4[1]); pk.y  = packh2(P4[2], P4[3]);
  tk2.x = packh2(T4[0], T4[1]); tk2.y = packh2(T4[2], T4[3]);
  *(float2*)(PTp + (size_t)rs * 1024 + 2 * j0)       = pk;
  *(float2*)(PTp + (size_t)rs * 1024 + 512 + 2 * j0) = tk2;
}

// K4: per-image mean of A_boost -> tiny MLP -> sigmoid gate. One block per image.
__global__ __launch_bounds__(256) void k4_gw(const float* __restrict__ A,
    const float* __restrict__ fc1w, const float* __restrict__ fc1b,
    const float* __restrict__ fc2w, const float* __restrict__ fc2b,
    float* __restrict__ gw){
  __shared__ float red[256];
  const int b = blockIdx.x, tid = threadIdx.x;
  const float4* img = (const float4*)(A + (size_t)b * 65536);
  float s = 0.f;
  for (int idx = tid; idx < 16384; idx += 256){
    const float4 v = img[idx];
    s += v.x + v.y + v.z + v.w;
  }
  red[tid] = s;
  __syncthreads();
  #pragma unroll
  for (int off = 128; off; off >>= 1){
    if (tid < off) red[tid] += red[tid + off];
    __syncthreads();
  }
  if (tid == 0){
    const float gf = red[0] * (1.0f / 65536.0f);
    float acc = fc2b[0];
    #pragma unroll
    for (int k = 0; k < 16; ++k)
      acc += fc2w[k] * fmaxf(gf * fc1w[k] + fc1b[k], 0.f);
    gw[b] = 1.f / (1.f + expf(-acc));
  }
}

// K5: 5 convs + fusion + BN + clamp -> staging (per slice).
__global__ __launch_bounds__(256) void k5_fuse(
    const float* __restrict__ Ap, const __half* __restrict__ PTh,
    const float* __restrict__ gwp,
    const float* __restrict__ theta_w, const float* __restrict__ theta_b,
    const float* __restrict__ phase_w, const float* __restrict__ phase_b,
    const float* __restrict__ phase_gamma, const float* __restrict__ phase_beta,
    const float* __restrict__ phase_mean, const float* __restrict__ phase_var,
    const float* __restrict__ ms_w1, const float* __restrict__ ms_b1,
    const float* __restrict__ ms_w2, const float* __restrict__ ms_b2,
    const float* __restrict__ ms_w3, const float* __restrict__ ms_b3,
    const float* __restrict__ fin_w, const float* __restrict__ fin_b,
    const float* __restrict__ fin_gamma, const float* __restrict__ fin_beta,
    const float* __restrict__ fin_mean, const float* __restrict__ fin_var,
    float* __restrict__ staging){
  const int zz = blockIdx.z;
  const int j = (blockIdx.x << 5) + (threadIdx.x & 31);
  const int i = (blockIdx.y << 3) + (threadIdx.x >> 5);
  const size_t rb = (size_t)zz << 8;

  auto ldA = [&](int ii, int jj) -> float {
    if ((unsigned)ii > 255u || (unsigned)jj > 255u) return 0.f;
    return Ap[((rb + ii) << 8) + jj];
  };
  auto ldP = [&](int ii, int jj) -> float {
    if ((unsigned)ii > 255u || (unsigned)jj > 255u) return 0.f;
    return __half2float(PTh[((rb + ii) << 9) + jj]);
  };
  auto ldT = [&](int ii, int jj) -> float {
    if ((unsigned)ii > 255u || (unsigned)jj > 255u) return 0.f;
    return __half2float(PTh[((rb + ii) << 9) + 256 + jj]);
  };

  float twl[9], pwl[9], w1[9], w2[9], w3[9];
  #pragma unroll
  for (int k = 0; k < 9; ++k){
    twl[k] = theta_w[k]; pwl[k] = phase_w[k];
    w1[k] = ms_w1[k]; w2[k] = ms_w2[k]; w3[k] = ms_w3[k];
  }
  float acc_t = theta_b[0], acc_p = phase_b[0];
  float m1 = ms_b1[0], m2 = ms_b2[0], m3 = ms_b3[0];
  #pragma unroll
  for (int dy = -1; dy <= 1; ++dy){
    #pragma unroll
    for (int dxk = -1; dxk <= 1; ++dxk){
      const int w = (dy + 1) * 3 + (dxk + 1);
      acc_t += twl[w] * ldT(i + dy, j + dxk);
      acc_p += pwl[w] * ldP(i + dy, j + dxk);
      m1 += w1[w] * ldA(i + dy, j + dxk);
      m2 += w2[w] * ldA(i + 2 * dy, j + 2 * dxk);
      m3 += w3[w] * ldA(i + 3 * dy, j + 3 * dxk);
    }
  }
  const float Abc = ldA(i, j);
  const float Thc = ldT(i, j);
  const float Gt = Thc / (1.f + expf(-acc_t));
  const float inv_p = phase_gamma[0] * rsqrtf(phase_var[0] + 1e-5f);
  const float Pp = fmaxf((acc_p - phase_mean[0]) * inv_p + phase_beta[0], 0.f);
  const float gwb = gwp[zz];
  const float pre = fin_w[0] * Abc + fin_w[1] * Pp + fin_w[2] * Gt
                  + gwb * (fin_w[3] * m1 + fin_w[4] * m2 + fin_w[5] * m3) + fin_b[0];
  const float inv_f = fin_gamma[0] * rsqrtf(fin_var[0] + 1e-5f);
  float o = (pre - fin_mean[0]) * inv_f + fin_beta[0];
  o = fminf(fmaxf(o, 0.f), 1.f);
  staging[((rb + i) << 8) + j] = o;
}

extern "C" void kernel_launch(void* const* d_in, const int* in_sizes, int n_in,
                              void* d_out, int out_size, void* d_ws, size_t ws_size,
                              hipStream_t stream){
  const float* x  = (const float*)d_in[0];
  const float* km = (const float*)d_in[1];

  char* ws    = (char*)d_ws;
  char* PT    = ws;                              // 67,108,864 B: per row 1024 B = [P fp16 x256 | T fp16 x256]
  char* SPECb = ws + 67108864ull;                // spectra / staging region: 134,217,728 / N bytes

  // Pick slice count N so that 64 MiB (PT) + 128 MiB / N (spectra) fits ws_size.
  int N = 2;
  while (N < 32 && 67108864ull + 134217728ull / (size_t)N > ws_size) N <<= 1;

  const int imgsPer = 256 / N;
  const int rowsPer = imgsPer * 256;
  const size_t sliceOutBytes = (size_t)rowsPer * 1024;   // = imgsPer*65536*4
  float* gwbuf   = (float*)(SPECb + sliceOutBytes);      // past staging, inside spectra region
  float* staging = (float*)SPECb;

  for (int s = 0; s < N; ++s){
    const float* xs = x + (size_t)s * rowsPer * 256;
    k1_row<<<rowsPer / 4, 256, 0, stream>>>(xs, (float2*)SPECb);
    k2_col<<<imgsPer * 32, 256, 0, stream>>>((float2*)SPECb, km);
    k3_rowinv<<<rowsPer / 4, 256, 0, stream>>>(xs, (const float2*)SPECb,
        (float*)d_out + (size_t)s * rowsPer * 256,
        PT + (size_t)s * rowsPer * 1024,
        (const float*)d_in[10], (const float*)d_in[11]);
  }

  k4_gw<<<256, 256, 0, stream>>>((const float*)d_out,
      (const float*)d_in[18], (const float*)d_in[19],
      (const float*)d_in[20], (const float*)d_in[21], gwbuf);

  for (int s = 0; s < N; ++s){
    k5_fuse<<<dim3(8, 32, imgsPer), 256, 0, stream>>>(
        (const float*)d_out + (size_t)s * rowsPer * 256,
        (const __half*)(PT + (size_t)s * rowsPer * 1024),
        gwbuf + (size_t)s * imgsPer,
        (const float*)d_in[2],  (const float*)d_in[3],
        (const float*)d_in[4],  (const float*)d_in[5],
        (const float*)d_in[6],  (const float*)d_in[7],
        (const float*)d_in[8],  (const float*)d_in[9],
        (const float*)d_in[12], (const float*)d_in[13],
        (const float*)d_in[14], (const float*)d_in[15],
        (const float*)d_in[16], (const float*)d_in[17],
        (const float*)d_in[22], (const float*)d_in[23],
        (const float*)d_in[24], (const float*)d_in[25],
        (const float*)d_in[26], (const float*)d_in[27],
        staging);
    hipMemcpyAsync((char*)d_out + (size_t)s * sliceOutBytes, staging,
                   sliceOutBytes, hipMemcpyDeviceToDevice, stream);
  }
}

// Round 3
// 391.242 us; speedup vs baseline: 1.8459x; 1.8459x over previous
//
#include <hip/hip_runtime.h>
#include <hip/hip_fp16.h>
#include <math.h>

#define PI_F 3.14159265358979323846f

// base-4 digit reversal of an 8-bit index
__device__ __forceinline__ unsigned dr4(unsigned n){
  return ((n & 3u) << 6) | (((n >> 2) & 3u) << 4) | (((n >> 4) & 3u) << 2) | ((n >> 6) & 3u);
}

__device__ __forceinline__ float2 cmul(float2 a, float2 b){
  return make_float2(a.x * b.x - a.y * b.y, a.x * b.y + a.y * b.x);
}

// tw[k] = e^{+2*pi*i*k/256}
__device__ __forceinline__ void fill_tw256(float2* tw, int tid){
  float s, c;
  sincosf((2.0f * PI_F / 256.0f) * (float)tid, &s, &c);
  tw[tid] = make_float2(c, s);
  __syncthreads();
}

// radix-4 DIT butterfly. INV=false: W=e^{-2pi i/len} (conj twiddles, W^q=-i); INV=true: +.
template<bool INV>
__device__ __forceinline__ void bfly4(float2 a, float2 b, float2 c, float2 d,
                                      float2 w1, float2 w2, float2 w3,
                                      float2& X0, float2& X1, float2& X2, float2& X3){
  if (!INV){ w1.y = -w1.y; w2.y = -w2.y; w3.y = -w3.y; }
  const float2 t1 = cmul(b, w1), t2 = cmul(c, w2), t3 = cmul(d, w3);
  const float2 s0 = make_float2(a.x + t2.x, a.y + t2.y);
  const float2 s1 = make_float2(a.x - t2.x, a.y - t2.y);
  const float2 s2 = make_float2(t1.x + t3.x, t1.y + t3.y);
  const float2 s3 = make_float2(t1.x - t3.x, t1.y - t3.y);
  X0 = make_float2(s0.x + s2.x, s0.y + s2.y);
  X2 = make_float2(s0.x - s2.x, s0.y - s2.y);
  if (!INV){
    X1 = make_float2(s1.x + s3.y, s1.y - s3.x);   // s1 - i*s3
    X3 = make_float2(s1.x - s3.y, s1.y + s3.x);   // s1 + i*s3
  } else {
    X1 = make_float2(s1.x - s3.y, s1.y + s3.x);
    X3 = make_float2(s1.x + s3.y, s1.y - s3.x);
  }
}

// 256-pt radix-4 DIT on contiguous float2 rows (1 or 2 buffers), 64 lanes, 1 bfly/lane/stage.
// Input digit-reversed, output natural.
template<bool INV, bool DUAL>
__device__ __forceinline__ void fft256_row(float2* A, float2* B, const float2* tw, int lane){
  #pragma unroll
  for (int s = 0; s < 4; ++s){
    const int q = 1 << (2 * s);
    const int m = 64 >> (2 * s);
    const int p = lane & (q - 1);
    const int base = ((lane >> (2 * s)) << (2 * s + 2)) + p;
    const float2 w1 = tw[p * m], w2 = tw[2 * p * m], w3 = tw[3 * p * m];
    {
      float2 X0, X1, X2, X3;
      bfly4<INV>(A[base], A[base + q], A[base + 2 * q], A[base + 3 * q], w1, w2, w3, X0, X1, X2, X3);
      A[base] = X0; A[base + q] = X1; A[base + 2 * q] = X2; A[base + 3 * q] = X3;
    }
    if (DUAL){
      float2 X0, X1, X2, X3;
      bfly4<INV>(B[base], B[base + q], B[base + 2 * q], B[base + 3 * q], w1, w2, w3, X0, X1, X2, X3);
      B[base] = X0; B[base + q] = X1; B[base + 2 * q] = X2; B[base + 3 * q] = X3;
    }
    __syncthreads();
  }
}

// 256-pt radix-4 DIT over 8 interleaved columns, float2 pitch 9. 256 thr = 8 col x 32 sub,
// 2 butterflies per thread per stage.
template<bool INV>
__device__ __forceinline__ void fft256_cols(float2* buf, const float2* tw, int c, int sub){
  #pragma unroll
  for (int s = 0; s < 4; ++s){
    const int q = 1 << (2 * s);
    const int m = 64 >> (2 * s);
    #pragma unroll
    for (int k = 0; k < 2; ++k){
      const int t = sub + (k << 5);
      const int p = t & (q - 1);
      const int base = ((t >> (2 * s)) << (2 * s + 2)) + p;
      const float2 w1 = tw[p * m], w2 = tw[2 * p * m], w3 = tw[3 * p * m];
      float2 X0, X1, X2, X3;
      bfly4<INV>(buf[base * 9 + c], buf[(base + q) * 9 + c],
                 buf[(base + 2 * q) * 9 + c], buf[(base + 3 * q) * 9 + c],
                 w1, w2, w3, X0, X1, X2, X3);
      buf[base * 9 + c] = X0; buf[(base + q) * 9 + c] = X1;
      buf[(base + 2 * q) * 9 + c] = X2; buf[(base + 3 * q) * 9 + c] = X3;
    }
    __syncthreads();
  }
}

__device__ __forceinline__ float packh2(float re, float im){
  __half2 h = __floats2half2_rn(re, im);
  return __builtin_bit_cast(float, h);
}
__device__ __forceinline__ float2 unpackh2(float p){
  return __half22float2(__builtin_bit_cast(__half2, p));
}
__device__ __forceinline__ unsigned packh2u(float a, float b){
  return __builtin_bit_cast(unsigned, __floats2half2_rn(a, b));
}

#define PLANE_PITCH 264
#define PLANE_ELEMS (264 * 264)   // 69696 elems per image (f32 or half2)

// K0: Riesz scale table sT[v*256+u] = clip(softplus(km[u,v]),1e-3,10)/(sqrt((u+1)^2+(v+1)^2)+1e-6)/65536
__global__ __launch_bounds__(256) void k0_prep(const float* __restrict__ km, float* __restrict__ sT){
  const int idx = blockIdx.x * 256 + threadIdx.x;
  const int u = idx >> 8, v = idx & 255;
  const float kv = km[idx];
  float sp = fmaxf(kv, 0.f) + log1pf(expf(-fabsf(kv)));
  sp = fminf(fmaxf(sp, 1e-3f), 10.f);
  const float fu = (float)(u + 1), fv = (float)(v + 1);
  sT[v * 256 + u] = sp / (sqrtf(fu * fu + fv * fv) + 1e-6f) * (1.0f / 65536.0f);
}

// K1: forward row FFT (over j). 4 rows/block.
__global__ __launch_bounds__(256) void k1_row(const float* __restrict__ xs, float2* __restrict__ SPEC){
  __shared__ float2 tw[256];
  __shared__ __align__(16) float2 buf[4][256];
  const int tid = threadIdx.x;
  fill_tw256(tw, tid);
  const int grp = tid >> 6, lane = tid & 63;
  const int rs = blockIdx.x * 4 + grp;
  const int j0 = lane << 2;
  const float4 xv = *(const float4*)(xs + (size_t)rs * 256 + j0);
  float2* rb = buf[grp];
  rb[dr4(j0 + 0)] = make_float2(xv.x, 0.f);
  rb[dr4(j0 + 1)] = make_float2(xv.y, 0.f);
  rb[dr4(j0 + 2)] = make_float2(xv.z, 0.f);
  rb[dr4(j0 + 3)] = make_float2(xv.w, 0.f);
  __syncthreads();
  fft256_row<false, false>(rb, (float2*)nullptr, tw, lane);
  float4* dst = (float4*)(SPEC + (size_t)rs * 256);
  const float4* src = (const float4*)rb;
  dst[lane * 2]     = src[lane * 2];
  dst[lane * 2 + 1] = src[lane * 2 + 1];
}

// K2: per (image, 8-col tile): col FFT -> F[v][u]; two Riesz filters; 2 col IFFTs;
// write U1,U2 packed fp16 in place over this block's own SPEC bytes.
__global__ __launch_bounds__(256) void k2_col(float2* SPEC, const float* __restrict__ sT){
  __shared__ float2 tw[256];
  __shared__ float2 bufA[256 * 9];
  __shared__ float2 bufB[256 * 9];
  const int tid = threadIdx.x;
  fill_tw256(tw, tid);
  const int b_local = blockIdx.x >> 5;
  const int u0 = (blockIdx.x & 31) << 3;
  const int c = tid & 7, sub = tid >> 3;
  const size_t rowbase = (size_t)b_local * 256;

  #pragma unroll
  for (int k = 0; k < 8; ++k){
    const int l = tid + (k << 8);
    const int r = l >> 3, cc = l & 7;
    bufA[dr4(r) * 9 + cc] = SPEC[(rowbase + r) * 256 + u0 + cc];
  }
  __syncthreads();
  fft256_cols<false>(bufA, tw, c, sub);             // F[v][u] natural in bufA

  float s8[8];
  #pragma unroll
  for (int k = 0; k < 8; ++k){
    const int l = tid + (k << 8);
    const int v = l >> 3, cc = l & 7;
    const int u = u0 + cc;
    const float s = sT[v * 256 + u];
    s8[k] = s;
    const float2 F = bufA[v * 9 + cc];
    const float s1 = (float)(v + 1) * s;            // dx filter: -i*(v+1)*s * F
    bufB[dr4(v) * 9 + cc] = make_float2(s1 * F.y, -s1 * F.x);
  }
  __syncthreads();
  fft256_cols<true>(bufB, tw, c, sub);

  float u1h[8];
  #pragma unroll
  for (int k = 0; k < 8; ++k){
    const int l = tid + (k << 8);
    const int i = l >> 3, cc = l & 7;
    const float2 f1 = bufB[i * 9 + cc];
    u1h[k] = packh2(f1.x, f1.y);
  }
  __syncthreads();

  #pragma unroll
  for (int k = 0; k < 8; ++k){
    const int l = tid + (k << 8);
    const int v = l >> 3, cc = l & 7;
    const int u = u0 + cc;
    const float2 F = bufA[v * 9 + cc];
    const float s2 = (float)(u + 1) * s8[k];        // dy filter: -i*(u+1)*s * F
    bufB[dr4(v) * 9 + cc] = make_float2(s2 * F.y, -s2 * F.x);
  }
  __syncthreads();
  fft256_cols<true>(bufB, tw, c, sub);

  #pragma unroll
  for (int k = 0; k < 8; ++k){
    const int l = tid + (k << 8);
    const int i = l >> 3, cc = l & 7;
    const float2 f2 = bufB[i * 9 + cc];
    float2 slot;
    slot.x = u1h[k];
    slot.y = packh2(f2.x, f2.y);
    SPEC[(rowbase + i) * 256 + u0 + cc] = slot;
  }
}

// K3: row IFFT of packed U1/U2 + pointwise; write padded A plane (f32) and PT plane (half2(P,T)).
__global__ __launch_bounds__(256) void k3_rowinv(const float* __restrict__ xs,
    const float2* __restrict__ SPEC, float* __restrict__ Ap, unsigned* __restrict__ PTp,
    const float* __restrict__ ampw, const float* __restrict__ ampb){
  __shared__ float2 tw[256];
  __shared__ __align__(16) float2 b1[4][256];
  __shared__ __align__(16) float2 b2[4][256];
  const int tid = threadIdx.x;
  fill_tw256(tw, tid);
  const int grp = tid >> 6, lane = tid & 63;
  const int rs = blockIdx.x * 4 + grp;
  const int j0 = lane << 2;
  const float4* srow = (const float4*)(SPEC + (size_t)rs * 256);
  const float4 qa = srow[lane * 2], qb = srow[lane * 2 + 1];
  b1[grp][dr4(j0 + 0)] = unpackh2(qa.x); b2[grp][dr4(j0 + 0)] = unpackh2(qa.y);
  b1[grp][dr4(j0 + 1)] = unpackh2(qa.z); b2[grp][dr4(j0 + 1)] = unpackh2(qa.w);
  b1[grp][dr4(j0 + 2)] = unpackh2(qb.x); b2[grp][dr4(j0 + 2)] = unpackh2(qb.y);
  b1[grp][dr4(j0 + 3)] = unpackh2(qb.z); b2[grp][dr4(j0 + 3)] = unpackh2(qb.w);
  __syncthreads();
  fft256_row<true, true>(b1[grp], b2[grp], tw, lane);

  const float aw = *ampw, ab = *ampb;
  const float4 xv = *(const float4*)(xs + (size_t)rs * 256 + j0);
  const float xa[4] = {xv.x, xv.y, xv.z, xv.w};
  float A4[4], P4[4], T4[4];
  #pragma unroll
  for (int k = 0; k < 4; ++k){
    const float2 r1 = b1[grp][j0 + k];
    const float2 r2 = b2[grp][j0 + k];
    const float R1 = sqrtf(r1.x * r1.x + r1.y * r1.y) + 1e-6f;
    const float R2 = sqrtf(r2.x * r2.x + r2.y * r2.y) + 1e-6f;
    const float xvv = xa[k];
    const float A = sqrtf(fmaxf(xvv * xvv + R1 * R1 + R2 * R2, 0.f) + 1e-6f);
    P4[k] = atan2f(sqrtf(R1 * R1 + R2 * R2) + 1e-6f, xvv + 1e-6f);
    T4[k] = atan2f(R2, R1 + 1e-6f);
    A4[k] = A + fmaxf(aw * A + ab, 0.f);
  }
  const int img = rs >> 8, i = rs & 255;
  float* arow = Ap + (size_t)img * PLANE_ELEMS + (size_t)(i + 4) * PLANE_PITCH + 4;
  *(float4*)(arow + j0) = make_float4(A4[0], A4[1], A4[2], A4[3]);
  unsigned* ptrow = PTp + (size_t)img * PLANE_ELEMS + (size_t)(i + 4) * PLANE_PITCH + 4;
  uint4 pk;
  pk.x = packh2u(P4[0], T4[0]); pk.y = packh2u(P4[1], T4[1]);
  pk.z = packh2u(P4[2], T4[2]); pk.w = packh2u(P4[3], T4[3]);
  *(uint4*)(ptrow + j0) = pk;
}

// KPAD: zero the 4-cell halo of both planes for one image per block.
__global__ __launch_bounds__(256) void kpad(float* __restrict__ Ap, unsigned* __restrict__ PTp){
  const int b = blockIdx.x, tid = threadIdx.x;
  float* A = Ap + (size_t)b * PLANE_ELEMS;
  unsigned* P = PTp + (size_t)b * PLANE_ELEMS;
  for (int idx = tid; idx < 4 * PLANE_PITCH; idx += 256){
    const int r = idx / PLANE_PITCH, c2 = idx % PLANE_PITCH;
    A[r * PLANE_PITCH + c2] = 0.f;          P[r * PLANE_PITCH + c2] = 0u;
    A[(260 + r) * PLANE_PITCH + c2] = 0.f;  P[(260 + r) * PLANE_PITCH + c2] = 0u;
  }
  for (int idx = tid; idx < 256 * 4; idx += 256){
    const int r = 4 + (idx >> 2), c2 = idx & 3;
    A[r * PLANE_PITCH + c2] = 0.f;          P[r * PLANE_PITCH + c2] = 0u;
    A[r * PLANE_PITCH + 260 + c2] = 0.f;    P[r * PLANE_PITCH + 260 + c2] = 0u;
  }
}

// K4: per-image mean of A -> MLP -> sigmoid gate. One block per image, one row per thread.
__global__ __launch_bounds__(256) void k4_gw(const float* __restrict__ Ap,
    const float* __restrict__ fc1w, const float* __restrict__ fc1b,
    const float* __restrict__ fc2w, const float* __restrict__ fc2b,
    float* __restrict__ gw){
  __shared__ float red[256];
  const int b = blockIdx.x, tid = threadIdx.x;
  const float4* row = (const float4*)(Ap + (size_t)b * PLANE_ELEMS + (size_t)(tid + 4) * PLANE_PITCH + 4);
  float s = 0.f;
  #pragma unroll 8
  for (int k = 0; k < 64; ++k){
    const float4 v = row[k];
    s += v.x + v.y + v.z + v.w;
  }
  red[tid] = s;
  __syncthreads();
  #pragma unroll
  for (int off = 128; off; off >>= 1){
    if (tid < off) red[tid] += red[tid + off];
    __syncthreads();
  }
  if (tid == 0){
    const float gf = red[0] * (1.0f / 65536.0f);
    float acc = fc2b[0];
    #pragma unroll
    for (int k = 0; k < 16; ++k)
      acc += fc2w[k] * fmaxf(gf * fc1w[k] + fc1b[k], 0.f);
    gw[b] = 1.f / (1.f + expf(-acc));
  }
}

// K5: register-blocked 4x4 per thread; padded planes, zero bounds checks; writes d_out directly.
__global__ __launch_bounds__(256) void k5_fuse(
    const float* __restrict__ Ap, const unsigned* __restrict__ PTp,
    const float* __restrict__ gwp,
    const float* __restrict__ theta_w, const float* __restrict__ theta_b,
    const float* __restrict__ phase_w, const float* __restrict__ phase_b,
    const float* __restrict__ phase_gamma, const float* __restrict__ phase_beta,
    const float* __restrict__ phase_mean, const float* __restrict__ phase_var,
    const float* __restrict__ ms_w1, const float* __restrict__ ms_b1,
    const float* __restrict__ ms_w2, const float* __restrict__ ms_b2,
    const float* __restrict__ ms_w3, const float* __restrict__ ms_b3,
    const float* __restrict__ fin_w, const float* __restrict__ fin_b,
    const float* __restrict__ fin_gamma, const float* __restrict__ fin_beta,
    const float* __restrict__ fin_mean, const float* __restrict__ fin_var,
    float* __restrict__ out){
  const int z = blockIdx.z;
  const int tx = threadIdx.x & 15, ty = threadIdx.x >> 4;
  const int j0 = (blockIdx.x << 6) + (tx << 2);
  const int i0 = (blockIdx.y << 6) + (ty << 2);
  const float* Abase = Ap + (size_t)z * PLANE_ELEMS;
  const unsigned* Pbase = PTp + (size_t)z * PLANE_ELEMS;

  float tw9[9], pw9[9], w1[9], w2[9], w3[9];
  #pragma unroll
  for (int k = 0; k < 9; ++k){
    tw9[k] = theta_w[k]; pw9[k] = phase_w[k];
    w1[k] = ms_w1[k]; w2[k] = ms_w2[k]; w3[k] = ms_w3[k];
  }
  const float b1s = ms_b1[0], b2s = ms_b2[0], b3s = ms_b3[0];
  const float tbs = theta_b[0], pbs = phase_b[0];

  float4 m1[4], m2[4], m3[4], at[4], ap[4], Ac[4], Tc[4];
  #pragma unroll
  for (int oi = 0; oi < 4; ++oi){
    m1[oi] = make_float4(b1s, b1s, b1s, b1s);
    m2[oi] = make_float4(b2s, b2s, b2s, b2s);
    m3[oi] = make_float4(b3s, b3s, b3s, b3s);
    at[oi] = make_float4(tbs, tbs, tbs, tbs);
    ap[oi] = make_float4(pbs, pbs, pbs, pbs);
  }

  // ---- A-plane contributions (rows i0-3 .. i0+6, cols j0-4 .. j0+7) ----
  #pragma unroll
  for (int lr = 0; lr < 10; ++lr){
    const int ar = i0 - 3 + lr;
    const float* rowp = Abase + (size_t)(ar + 4) * PLANE_PITCH + j0;
    const float4 va = *(const float4*)(rowp);
    const float4 vb = *(const float4*)(rowp + 4);
    const float4 vc = *(const float4*)(rowp + 8);
    const float a[12] = {va.x, va.y, va.z, va.w, vb.x, vb.y, vb.z, vb.w, vc.x, vc.y, vc.z, vc.w};
    #pragma unroll
    for (int oi = 0; oi < 4; ++oi){
      const int dd = lr - 3 - oi;      // = dy * dilation
      if (dd >= -1 && dd <= 1){
        const int wr = (dd + 1) * 3;
        #pragma unroll
        for (int dx = -1; dx <= 1; ++dx){
          const float w = w1[wr + dx + 1];
          m1[oi].x += w * a[4 + 0 + dx]; m1[oi].y += w * a[4 + 1 + dx];
          m1[oi].z += w * a[4 + 2 + dx]; m1[oi].w += w * a[4 + 3 + dx];
        }
      }
      if (dd == -2 || dd == 0 || dd == 2){
        const int wr = (dd / 2 + 1) * 3;
        #pragma unroll
        for (int dx = -1; dx <= 1; ++dx){
          const float w = w2[wr + dx + 1];
          m2[oi].x += w * a[4 + 0 + 2 * dx]; m2[oi].y += w * a[4 + 1 + 2 * dx];
          m2[oi].z += w * a[4 + 2 + 2 * dx]; m2[oi].w += w * a[4 + 3 + 2 * dx];
        }
      }
      if (dd == -3 || dd == 0 || dd == 3){
        const int wr = (dd / 3 + 1) * 3;
        #pragma unroll
        for (int dx = -1; dx <= 1; ++dx){
          const float w = w3[wr + dx + 1];
          m3[oi].x += w * a[4 + 0 + 3 * dx]; m3[oi].y += w * a[4 + 1 + 3 * dx];
          m3[oi].z += w * a[4 + 2 + 3 * dx]; m3[oi].w += w * a[4 + 3 + 3 * dx];
        }
      }
      if (dd == 0) Ac[oi] = make_float4(a[4], a[5], a[6], a[7]);
    }
  }

  // ---- PT-plane contributions (rows i0-1 .. i0+4) ----
  #pragma unroll
  for (int lr = 0; lr < 6; ++lr){
    const int ar = i0 - 1 + lr;
    const unsigned* rowp = Pbase + (size_t)(ar + 4) * PLANE_PITCH + j0;
    const uint4 ua = *(const uint4*)(rowp);
    const uint4 ub = *(const uint4*)(rowp + 4);
    const uint4 uc = *(const uint4*)(rowp + 8);
    const unsigned uu[12] = {ua.x, ua.y, ua.z, ua.w, ub.x, ub.y, ub.z, ub.w, uc.x, uc.y, uc.z, uc.w};
    float p[12], t[12];
    #pragma unroll
    for (int k = 0; k < 12; ++k){
      const float2 pt = __half22float2(__builtin_bit_cast(__half2, uu[k]));
      p[k] = pt.x; t[k] = pt.y;
    }
    #pragma unroll
    for (int oi = 0; oi < 4; ++oi){
      const int dd = lr - 1 - oi;
      if (dd >= -1 && dd <= 1){
        const int wr = (dd + 1) * 3;
        #pragma unroll
        for (int dx = -1; dx <= 1; ++dx){
          const float wp = pw9[wr + dx + 1], wt = tw9[wr + dx + 1];
          ap[oi].x += wp * p[4 + 0 + dx]; ap[oi].y += wp * p[4 + 1 + dx];
          ap[oi].z += wp * p[4 + 2 + dx]; ap[oi].w += wp * p[4 + 3 + dx];
          at[oi].x += wt * t[4 + 0 + dx]; at[oi].y += wt * t[4 + 1 + dx];
          at[oi].z += wt * t[4 + 2 + dx]; at[oi].w += wt * t[4 + 3 + dx];
        }
      }
      if (dd == 0) Tc[oi] = make_float4(t[4], t[5], t[6], t[7]);
    }
  }

  // ---- epilogue ----
  const float gwb = gwp[z];
  const float inv_p = phase_gamma[0] * rsqrtf(phase_var[0] + 1e-5f);
  const float pmean = phase_mean[0], pbeta = phase_beta[0];
  const float f0 = fin_w[0], f1 = fin_w[1], f2 = fin_w[2];
  const float f3 = fin_w[3], f4 = fin_w[4], f5 = fin_w[5];
  const float fb = fin_b[0];
  const float inv_f = fin_gamma[0] * rsqrtf(fin_var[0] + 1e-5f);
  const float fmean = fin_mean[0], fbeta = fin_beta[0];

  #pragma unroll
  for (int oi = 0; oi < 4; ++oi){
    float o4[4];
    const float mm1[4] = {m1[oi].x, m1[oi].y, m1[oi].z, m1[oi].w};
    const float mm2[4] = {m2[oi].x, m2[oi].y, m2[oi].z, m2[oi].w};
    const float mm3[4] = {m3[oi].x, m3[oi].y, m3[oi].z, m3[oi].w};
    const float tt[4]  = {at[oi].x, at[oi].y, at[oi].z, at[oi].w};
    const float pp[4]  = {ap[oi].x, ap[oi].y, ap[oi].z, ap[oi].w};
    const float ac[4]  = {Ac[oi].x, Ac[oi].y, Ac[oi].z, Ac[oi].w};
    const float tc[4]  = {Tc[oi].x, Tc[oi].y, Tc[oi].z, Tc[oi].w};
    #pragma unroll
    for (int oj = 0; oj < 4; ++oj){
      const float Gt = tc[oj] / (1.f + expf(-tt[oj]));
      const float Pp = fmaxf((pp[oj] - pmean) * inv_p + pbeta, 0.f);
      const float pre = f0 * ac[oj] + f1 * Pp + f2 * Gt
                      + gwb * (f3 * mm1[oj] + f4 * mm2[oj] + f5 * mm3[oj]) + fb;
      float o = (pre - fmean) * inv_f + fbeta;
      o4[oj] = fminf(fmaxf(o, 0.f), 1.f);
    }
    *(float4*)(out + ((size_t)(z * 256 + i0 + oi) << 8) + j0) = make_float4(o4[0], o4[1], o4[2], o4[3]);
  }
}

extern "C" void kernel_launch(void* const* d_in, const int* in_sizes, int n_in,
                              void* d_out, int out_size, void* d_ws, size_t ws_size,
                              hipStream_t stream){
  const float* x  = (const float*)d_in[0];
  const float* km = (const float*)d_in[1];

  // Per-slice layout: Aplane | PTplane | SPEC ; then global sTab | gw.
  // per-image: 278784 B (A) + 278784 B (PT) + 524288 B (SPEC) = 1,081,856 B.
  int N = 1;
  while (N < 64){
    const size_t need = (size_t)(256 / N) * 1081856ull + 262144ull + 1024ull;
    if (need <= ws_size) break;
    N <<= 1;
  }
  const int imgsPer = 256 / N;
  const int rowsPer = imgsPer * 256;

  char* ws = (char*)d_ws;
  float*    Aplane = (float*)ws;
  unsigned* PTplane = (unsigned*)(ws + (size_t)imgsPer * 278784ull);
  float2*   SPEC   = (float2*)(ws + (size_t)imgsPer * 557568ull);
  float*    sTab   = (float*)(ws + (size_t)imgsPer * 1081856ull);
  float*    gwbuf  = (float*)(ws + (size_t)imgsPer * 1081856ull + 262144ull);

  k0_prep<<<256, 256, 0, stream>>>(km, sTab);

  for (int s = 0; s < N; ++s){
    const float* xs = x + (size_t)s * rowsPer * 256;
    float* outs = (float*)d_out + (size_t)s * rowsPer * 256;

    k1_row<<<rowsPer / 4, 256, 0, stream>>>(xs, SPEC);
    k2_col<<<imgsPer * 32, 256, 0, stream>>>(SPEC, sTab);
    k3_rowinv<<<rowsPer / 4, 256, 0, stream>>>(xs, SPEC, Aplane, PTplane,
        (const float*)d_in[10], (const float*)d_in[11]);
    kpad<<<imgsPer, 256, 0, stream>>>(Aplane, PTplane);
    k4_gw<<<imgsPer, 256, 0, stream>>>(Aplane,
        (const float*)d_in[18], (const float*)d_in[19],
        (const float*)d_in[20], (const float*)d_in[21], gwbuf);
    k5_fuse<<<dim3(4, 4, imgsPer), 256, 0, stream>>>(
        Aplane, PTplane, gwbuf,
        (const float*)d_in[2],  (const float*)d_in[3],
        (const float*)d_in[4],  (const float*)d_in[5],
        (const float*)d_in[6],  (const float*)d_in[7],
        (const float*)d_in[8],  (const float*)d_in[9],
        (const float*)d_in[12], (const float*)d_in[13],
        (const float*)d_in[14], (const float*)d_in[15],
        (const float*)d_in[16], (const float*)d_in[17],
        (const float*)d_in[22], (const float*)d_in[23],
        (const float*)d_in[24], (const float*)d_in[25],
        (const float*)d_in[26], (const float*)d_in[27],
        outs);
  }
}